// Round 7
// baseline (220.008 us; speedup 1.0000x reference)
//
#include <hip/hip_runtime.h>
#include <math.h>

#define NCLU 10
#define D    64
#define NSLOT 4096

typedef unsigned int   u32;
typedef unsigned short u16;

typedef __attribute__((ext_vector_type(8))) short  bf16x8;
typedef __attribute__((ext_vector_type(4))) float  f32x4;

__device__ __forceinline__ u16 f2bf_rne(float f) {
    u32 u = __float_as_uint(f);
    return (u16)((u + 0x7fffu + ((u >> 16) & 1u)) >> 16);
}

__device__ __forceinline__ bf16x8 pack8(float4 a, float4 b) {
    bf16x8 r;
    r[0] = (short)f2bf_rne(a.x); r[1] = (short)f2bf_rne(a.y);
    r[2] = (short)f2bf_rne(a.z); r[3] = (short)f2bf_rne(a.w);
    r[4] = (short)f2bf_rne(b.x); r[5] = (short)f2bf_rne(b.y);
    r[6] = (short)f2bf_rne(b.z); r[7] = (short)f2bf_rne(b.w);
    return r;
}

__device__ __forceinline__ float wred(float v) {
#pragma unroll
    for (int off = 32; off > 0; off >>= 1) v += __shfl_xor(v, off);
    return v;
}

// Load a 64x64 f32 weight matrix as MFMA A-fragments (bf16): a[mt][kt], lane (quad,lc)
// holds W[16*mt+lc][kt*32 + quad*8 .. +7]. 32 VGPRs total per wave.
__device__ __forceinline__ void load_afrags64(bf16x8 a[4][2], const float* __restrict__ W,
                                              int lc, int quad) {
#pragma unroll
    for (int mt = 0; mt < 4; ++mt)
#pragma unroll
        for (int kt = 0; kt < 2; ++kt) {
            const float* p = W + (16 * mt + lc) * 64 + kt * 32 + quad * 8;
            a[mt][kt] = pack8(*(const float4*)p, *(const float4*)(p + 4));
        }
}

__device__ __forceinline__ void load_afrags128(bf16x8 a[4][2], const float* __restrict__ W,
                                               int ktbase, int lc, int quad) {
#pragma unroll
    for (int mt = 0; mt < 4; ++mt)
#pragma unroll
        for (int kt = 0; kt < 2; ++kt) {
            const float* p = W + (16 * mt + lc) * 128 + (ktbase + kt) * 32 + quad * 8;
            a[mt][kt] = pack8(*(const float4*)p, *(const float4*)(p + 4));
        }
}

__device__ __forceinline__ bf16x8 bfrag(const float* __restrict__ xbase, int xstride,
                                        int lc, int quad, int ktglob) {
    if (lc < NCLU) {
        const float* p = xbase + lc * xstride + ktglob * 32 + quad * 8;
        return pack8(*(const float4*)p, *(const float4*)(p + 4));
    }
    bf16x8 z;
#pragma unroll
    for (int j = 0; j < 8; ++j) z[j] = 0;
    return z;
}

__device__ __forceinline__ void mm_apply(const bf16x8 a[4][2], const float* __restrict__ xbase,
                                         int xstride, int ktbase,
                                         float* __restrict__ obase, int ostride, int ooff,
                                         const float* __restrict__ bias, bool do_relu,
                                         int lc, int quad) {
    f32x4 acc[4];
#pragma unroll
    for (int mt = 0; mt < 4; ++mt) acc[mt] = (f32x4){0.f, 0.f, 0.f, 0.f};
#pragma unroll
    for (int kt = 0; kt < 2; ++kt) {
        bf16x8 b = bfrag(xbase, xstride, lc, quad, ktbase + kt);
#pragma unroll
        for (int mt = 0; mt < 4; ++mt)
            acc[mt] = __builtin_amdgcn_mfma_f32_16x16x32_bf16(a[mt][kt], b, acc[mt], 0, 0, 0);
    }
    if (lc < NCLU) {
#pragma unroll
        for (int mt = 0; mt < 4; ++mt) {
            float4 o;
            o.x = acc[mt][0]; o.y = acc[mt][1]; o.z = acc[mt][2]; o.w = acc[mt][3];
            if (bias) {
                float4 bv = *(const float4*)(bias + 16 * mt + 4 * quad);
                o.x += bv.x; o.y += bv.y; o.z += bv.z; o.w += bv.w;
            }
            if (do_relu) {
                o.x = fmaxf(o.x, 0.f); o.y = fmaxf(o.y, 0.f);
                o.z = fmaxf(o.z, 0.f); o.w = fmaxf(o.w, 0.f);
            }
            *(float4*)(obase + lc * ostride + ooff + 16 * mt + 4 * quad) = o;
        }
    }
}

// ---------------- Phase 1: MFMA weight-stationary slot-attention ----------------
// (unchanged from round 6 — dropped from 75 us to <47 us; phase2 is now the target)
__global__ __launch_bounds__(640, 3) void phase1_kernel(
    const float* __restrict__ cc0,
    const float* __restrict__ Wk, const float* __restrict__ bk,
    const float* __restrict__ Wq, const float* __restrict__ bq,
    const float* __restrict__ Wv, const float* __restrict__ bv,
    const float* __restrict__ cc_g, const float* __restrict__ cc_b,
    const float* __restrict__ W_ih, const float* __restrict__ W_hh,
    const float* __restrict__ b_ih, const float* __restrict__ b_hh,
    const float* __restrict__ ln_g, const float* __restrict__ ln_b,
    const float* __restrict__ W1, const float* __restrict__ b1,
    const float* __restrict__ W2, const float* __restrict__ b2,
    float* __restrict__ cc_out)
{
    const int t = threadIdx.x;
    const int w = t >> 6;
    const int i = t & 63;
    const int quad = i >> 4;
    const int lc   = i & 15;

    __shared__ float ccl[NCLU][68];
    __shared__ float xl[NCLU][68];
    __shared__ float kl[NCLU][68];
    __shared__ float vl[NCLU][68];
    __shared__ float ql[NCLU][68];
    __shared__ float ul[NCLU][68];
    __shared__ float hl[NCLU][68];
    __shared__ float dl9[NCLU][68];
    __shared__ float dl8[NCLU][68];
    __shared__ float tl[NCLU][132];
    __shared__ float gl[6][NCLU][68];
    __shared__ float al[NCLU][12];

    const float g_cc = cc_g[i], b_cc = cc_b[i];
    const float g_ln = ln_g[i], b_ln = ln_b[i];

    bf16x8 afrA[4][2], afrB[4][2];
#pragma unroll
    for (int mt = 0; mt < 4; ++mt)
#pragma unroll
        for (int kt = 0; kt < 2; ++kt) {
#pragma unroll
            for (int j = 0; j < 8; ++j) { afrA[mt][kt][j] = 0; afrB[mt][kt][j] = 0; }
        }

    const float* biasA = nullptr;
    if (w == 0)      { load_afrags64(afrA, Wq, lc, quad);                    biasA = bq; }
    else if (w <= 3) { load_afrags64(afrA, W_ih + (w - 1) * 64 * 64, lc, quad); biasA = b_ih + (w - 1) * 64; }
    else if (w <= 6) { load_afrags64(afrA, W_hh + (w - 4) * 64 * 64, lc, quad); biasA = b_hh + (w - 4) * 64; }
    else if (w == 7) { load_afrags64(afrA, Wk, lc, quad); }
    else if (w == 8) { load_afrags64(afrA, Wv, lc, quad);
                       load_afrags128(afrB, W2, 2, lc, quad); }
    else             { load_afrags128(afrA, W2, 0, lc, quad); biasA = b2; }

    float c = cc0[w * 64 + i];
    ccl[w][i] = c;
    __syncthreads();

    if (w == 7)      mm_apply(afrA, &ccl[0][0], 68, 0, &kl[0][0], 68, 0, bk, false, lc, quad);
    else if (w == 8) mm_apply(afrA, &ccl[0][0], 68, 0, &vl[0][0], 68, 0, bv, false, lc, quad);
    __syncthreads();

    if (w == 7)      { load_afrags64(afrA, W1, lc, quad);            biasA = b1; }
    else if (w == 8) { load_afrags64(afrA, W1 + 64 * 64, lc, quad);  biasA = b1 + 64; }

    for (int it = 0; it < 3; ++it) {
        {
            float s1 = wred(c), s2 = wred(c * c);
            float mu = s1 * (1.f / 64.f);
            float va = s2 * (1.f / 64.f) - mu * mu;
            xl[w][i] = (c - mu) * rsqrtf(va + 1e-5f) * g_cc + b_cc;
        }
        __syncthreads();

        if (w == 0)
            mm_apply(afrA, &xl[0][0], 68, 0, &ql[0][0], 68, 0, biasA, false, lc, quad);
        else if (w >= 4 && w <= 6)
            mm_apply(afrA, &ccl[0][0], 68, 0, &gl[w - 1][0][0], 68, 0, biasA, false, lc, quad);
        __syncthreads();

        if (i < NCLU) {
            const float4* kf = (const float4*)&kl[w][0];
            const float4* qf = (const float4*)&ql[i][0];
            float a0 = 0.f, a1 = 0.f, a2 = 0.f, a3 = 0.f;
#pragma unroll
            for (int jj = 0; jj < 16; ++jj) {
                float4 kv = kf[jj], qv = qf[jj];
                a0 += kv.x * qv.x; a1 += kv.y * qv.y; a2 += kv.z * qv.z; a3 += kv.w * qv.w;
            }
            al[w][i] = ((a0 + a1) + (a2 + a3)) * 0.125f;
        }
        __syncthreads();

        if (t < NCLU) {
            float mx = -1e30f;
#pragma unroll
            for (int nn = 0; nn < NCLU; ++nn) mx = fmaxf(mx, al[nn][t]);
            float e[NCLU]; float s = 0.f;
#pragma unroll
            for (int nn = 0; nn < NCLU; ++nn) { e[nn] = __expf(al[nn][t] - mx); s += e[nn]; }
            float inv = 1.f / s;
#pragma unroll
            for (int nn = 0; nn < NCLU; ++nn) al[nn][t] = e[nn] * inv + 1e-8f;
        }
        __syncthreads();
        if (t < NCLU) {
            float s = 0.f;
#pragma unroll
            for (int m = 0; m < NCLU; ++m) s += al[t][m];
            float inv = 1.f / s;
#pragma unroll
            for (int m = 0; m < NCLU; ++m) al[t][m] *= inv;
        }
        __syncthreads();

        {
            float u = 0.f;
#pragma unroll
            for (int m = 0; m < NCLU; ++m) u += al[w][m] * vl[m][i];
            ul[w][i] = u;
        }
        __syncthreads();

        if (w >= 1 && w <= 3)
            mm_apply(afrA, &ul[0][0], 68, 0, &gl[w - 1][0][0], 68, 0, biasA, false, lc, quad);
        __syncthreads();

        {
            float ir = gl[0][w][i], iz = gl[1][w][i], inn = gl[2][w][i];
            float hr = gl[3][w][i], hz = gl[4][w][i], hn = gl[5][w][i];
            float r = 1.f / (1.f + __expf(-(ir + hr)));
            float z = 1.f / (1.f + __expf(-(iz + hz)));
            float nn2 = tanhf(inn + r * hn);
            c = (1.f - z) * nn2 + z * c;

            float s1 = wred(c), s2 = wred(c * c);
            float mu = s1 * (1.f / 64.f);
            float va = s2 * (1.f / 64.f) - mu * mu;
            hl[w][i] = (c - mu) * rsqrtf(va + 1e-5f) * g_ln + b_ln;
        }
        __syncthreads();

        if (w == 7)
            mm_apply(afrA, &hl[0][0], 68, 0, &tl[0][0], 132, 0, biasA, true, lc, quad);
        else if (w == 8)
            mm_apply(afrA, &hl[0][0], 68, 0, &tl[0][0], 132, 64, biasA, true, lc, quad);
        __syncthreads();

        if (w == 9)
            mm_apply(afrA, &tl[0][0], 132, 0, &dl9[0][0], 68, 0, biasA, false, lc, quad);
        else if (w == 8)
            mm_apply(afrB, &tl[0][0], 132, 2, &dl8[0][0], 68, 0, nullptr, false, lc, quad);
        __syncthreads();

        c += dl9[w][i] + dl8[w][i];
        ccl[w][i] = c;
        __syncthreads();
    }

    cc_out[w * 64 + i] = c;
}

// ---------------- Phase 2: bf16-MFMA per-slot MLP + max over clusters ----------------
// ROUND-7 CHANGE: __launch_bounds__(64, 4) -> VGPR cap 128 (round 6 allocator picked 64,
// which couldn't hold rg[16] => serialized vmcnt waits; counters showed latency-bound:
// VALUBusy 10%, hbm 17%, occupancy 28%, nothing saturated). With 128 VGPRs all 16 loads
// of each weight matrix stay in flight behind a single wait. cc/bias loads hoisted to
// overlap the weight-load latency.
#define WSTRIDE 72
__global__ __launch_bounds__(64, 4) void phase2_kernel(
    const float* __restrict__ Wa, const float* __restrict__ ba,
    const float* __restrict__ Wb, const float* __restrict__ bb,
    const float* __restrict__ cc, float* __restrict__ out)
{
    const int s = blockIdx.x;
    const int l = threadIdx.x;
    const int quad = l >> 4;
    const int lc   = l & 15;

    __shared__ u16 Wlds[64 * WSTRIDE];
    __shared__ u16 hT[16 * WSTRIDE];

    const float* wa = Wa + (size_t)s * 4096;
    const float* wb = Wb + (size_t)s * 4096;

    // ---- issue all 16 Wa loads (coalesced 1KB/instr), plus cc + bias early ----
    float4 rg[16];
#pragma unroll
    for (int cch = 0; cch < 16; ++cch)
        rg[cch] = *(const float4*)(wa + cch * 256 + l * 4);

    // cc B-fragments (tiny, L2-resident) — built while Wa is in flight
    bf16x8 bfc[2];
#pragma unroll
    for (int kt = 0; kt < 2; ++kt) {
        if (lc < NCLU) {
            const float* cp = cc + lc * 64 + kt * 32 + quad * 8;
            bfc[kt] = pack8(*(const float4*)cp, *(const float4*)(cp + 4));
        } else {
#pragma unroll
            for (int j = 0; j < 8; ++j) bfc[kt][j] = 0;
        }
    }
    const float4 bav[4] = {
        *(const float4*)(ba + s * 64 + 0  + quad * 4),
        *(const float4*)(ba + s * 64 + 16 + quad * 4),
        *(const float4*)(ba + s * 64 + 32 + quad * 4),
        *(const float4*)(ba + s * 64 + 48 + quad * 4),
    };

    // ---- cvt + stage Wa into padded LDS ----
#pragma unroll
    for (int cch = 0; cch < 16; ++cch) {
        int row = cch * 4 + quad;
        u32 p0 = (u32)f2bf_rne(rg[cch].x) | ((u32)f2bf_rne(rg[cch].y) << 16);
        u32 p1 = (u32)f2bf_rne(rg[cch].z) | ((u32)f2bf_rne(rg[cch].w) << 16);
        uint2 pk; pk.x = p0; pk.y = p1;
        *(uint2*)(&Wlds[row * WSTRIDE + lc * 4]) = pk;
    }

    // ---- issue all 16 Wb loads (in flight across layer-1 compute) ----
#pragma unroll
    for (int cch = 0; cch < 16; ++cch)
        rg[cch] = *(const float4*)(wb + cch * 256 + l * 4);

    // ---- layer 1: D1 = Wa @ cc^T ----
    f32x4 acc[4];
#pragma unroll
    for (int mt = 0; mt < 4; ++mt) acc[mt] = (f32x4){0.f, 0.f, 0.f, 0.f};
#pragma unroll
    for (int kt = 0; kt < 2; ++kt) {
#pragma unroll
        for (int mt = 0; mt < 4; ++mt) {
            bf16x8 af = *(const bf16x8*)(&Wlds[(16 * mt + lc) * WSTRIDE + kt * 32 + quad * 8]);
            acc[mt] = __builtin_amdgcn_mfma_f32_16x16x32_bf16(af, bfc[kt], acc[mt], 0, 0, 0);
        }
    }

    // ---- epilogue L1: h = relu(D1 + ba); store hT[n][k] ----
#pragma unroll
    for (int mt = 0; mt < 4; ++mt) {
        u16 h0 = f2bf_rne(fmaxf(acc[mt][0] + bav[mt].x, 0.f));
        u16 h1 = f2bf_rne(fmaxf(acc[mt][1] + bav[mt].y, 0.f));
        u16 h2 = f2bf_rne(fmaxf(acc[mt][2] + bav[mt].z, 0.f));
        u16 h3 = f2bf_rne(fmaxf(acc[mt][3] + bav[mt].w, 0.f));
        uint2 pk; pk.x = (u32)h0 | ((u32)h1 << 16); pk.y = (u32)h2 | ((u32)h3 << 16);
        *(uint2*)(&hT[lc * WSTRIDE + 16 * mt + quad * 4]) = pk;
    }

    // ---- stage Wb ----
#pragma unroll
    for (int cch = 0; cch < 16; ++cch) {
        int row = cch * 4 + quad;
        u32 p0 = (u32)f2bf_rne(rg[cch].x) | ((u32)f2bf_rne(rg[cch].y) << 16);
        u32 p1 = (u32)f2bf_rne(rg[cch].z) | ((u32)f2bf_rne(rg[cch].w) << 16);
        uint2 pk; pk.x = p0; pk.y = p1;
        *(uint2*)(&Wlds[row * WSTRIDE + lc * 4]) = pk;
    }

    // ---- layer 2: D2 = Wb @ h ----
    f32x4 acc2[4];
#pragma unroll
    for (int mt = 0; mt < 4; ++mt) acc2[mt] = (f32x4){0.f, 0.f, 0.f, 0.f};
#pragma unroll
    for (int kt = 0; kt < 2; ++kt) {
        bf16x8 bf = *(const bf16x8*)(&hT[lc * WSTRIDE + kt * 32 + quad * 8]);
#pragma unroll
        for (int mt = 0; mt < 4; ++mt) {
            bf16x8 af = *(const bf16x8*)(&Wlds[(16 * mt + lc) * WSTRIDE + kt * 32 + quad * 8]);
            acc2[mt] = __builtin_amdgcn_mfma_f32_16x16x32_bf16(af, bf, acc2[mt], 0, 0, 0);
        }
    }

    // ---- max over clusters (butterfly over n=lc lanes, mask n>=10) ----
    const float NEG = -3.0e38f;
#pragma unroll
    for (int mt = 0; mt < 4; ++mt) {
#pragma unroll
        for (int r = 0; r < 4; ++r) {
            float v = (lc < NCLU) ? acc2[mt][r] : NEG;
#pragma unroll
            for (int off = 1; off < 16; off <<= 1)
                v = fmaxf(v, __shfl_xor(v, off));
            acc2[mt][r] = v;
        }
    }

    if (lc < 4) {
#pragma unroll
        for (int mt = 0; mt < 4; ++mt) {
            int row = 16 * mt + 4 * quad + lc;
            out[s * 64 + row] = acc2[mt][lc] + bb[s * 64 + row];
        }
    }
}

extern "C" void kernel_launch(void* const* d_in, const int* in_sizes, int n_in,
                              void* d_out, int out_size, void* d_ws, size_t ws_size,
                              hipStream_t stream) {
    const float* cc0  = (const float*)d_in[0];
    const float* Wk   = (const float*)d_in[1];
    const float* bk   = (const float*)d_in[2];
    const float* Wq   = (const float*)d_in[3];
    const float* bq   = (const float*)d_in[4];
    const float* Wv   = (const float*)d_in[5];
    const float* bv   = (const float*)d_in[6];
    const float* ccg  = (const float*)d_in[7];
    const float* ccb  = (const float*)d_in[8];
    const float* Wih  = (const float*)d_in[9];
    const float* Whh  = (const float*)d_in[10];
    const float* bih  = (const float*)d_in[11];
    const float* bhh  = (const float*)d_in[12];
    const float* lng  = (const float*)d_in[13];
    const float* lnb  = (const float*)d_in[14];
    const float* W1   = (const float*)d_in[15];
    const float* b1   = (const float*)d_in[16];
    const float* W2   = (const float*)d_in[17];
    const float* b2   = (const float*)d_in[18];
    const float* Wa   = (const float*)d_in[19];
    const float* ba   = (const float*)d_in[20];
    const float* Wb   = (const float*)d_in[21];
    const float* bb   = (const float*)d_in[22];

    float* cc_ws = (float*)d_ws;     // 640 floats
    float* out   = (float*)d_out;

    hipLaunchKernelGGL(phase1_kernel, dim3(1), dim3(640), 0, stream,
                       cc0, Wk, bk, Wq, bq, Wv, bv, ccg, ccb,
                       Wih, Whh, bih, bhh, lng, lnb, W1, b1, W2, b2, cc_ws);

    hipLaunchKernelGGL(phase2_kernel, dim3(NSLOT), dim3(64), 0, stream,
                       Wa, ba, Wb, bb, cc_ws, out);
}